// Round 3
// baseline (714.586 us; speedup 1.0000x reference)
//
#include <hip/hip_runtime.h>
#include <hip/hip_cooperative_groups.h>
#include <cstdint>

namespace cg = cooperative_groups;

#define D_CH 128
#define T_LEN 1024
#define ROWLEN 384
#define NROWS (128 * 1024)
#define TILE 64
#define NCHUNK (NROWS / TILE)   // 2048
#define VSTR_B 272              // vs row stride bytes (136 f16) — conflict-free b128 reads
#define EPI_W 132               // epi row stride words (pad 4) — 2-way max banks on scatter
#define WSLICE 8704             // per-wave slice: 2 vh panes (2*4352); epi (8448) aliases
#define MEAN_OFF (4 * WSLICE)   // mean_lds after the 4 wave slices
#define SMEM_B (MEAN_OFF + 512) // 35328 B -> 4 blocks/CU (141KB of 160KB)

typedef __attribute__((ext_vector_type(8))) _Float16 f16x8;
typedef __attribute__((ext_vector_type(4))) _Float16 f16x4;
typedef __attribute__((ext_vector_type(4))) float f32x4;

// ============================ FUSED COOPERATIVE PATH ============================
// One kernel, 1024 blocks x 2 chunks. Key identity (makes phase A mean-free):
//   smooth = (p*y)@K - p@(diag(mean)K) + mean,   p = softmax(w)
// Phase A: load y,w ONCE (y was previously read twice: prep + main); exp; intensity
//   store; softmax; LDS-transpose p*y and p into MFMA A-frags (held in regs);
//   deterministic partial sums of y -> part[bid][128].
// grid.sync (with explicit agent fences for cross-XCD L2 visibility).
// Phase B: mean = sum of 8 partials /1024 (staged in LDS); B2-frag = Kfrag * (-mean[k])
//   via packed f16 muls; BOTH matmuls accumulate into one acc; epilogue as before.
__global__ __launch_bounds__(256, 4) void fused_kernel(const float* __restrict__ x,
                                                       const float* __restrict__ Kmat,
                                                       float* __restrict__ part,
                                                       _Float16* __restrict__ Ktg,
                                                       float* __restrict__ out) {
  __shared__ alignas(16) char smem[SMEM_B];
  cg::grid_group grid = cg::this_grid();
  int bid = blockIdx.x;
  int tid = threadIdx.x;
  int wave = tid >> 6, lane = tid & 63;
  int hf = lane >> 5, li = lane & 31;
  int c0 = 4 * li;
  int m0 = wave * 16;
  int l15 = lane & 15, lg = lane >> 4;
  char* vs1 = smem + wave * WSLICE;
  char* vs2 = vs1 + 4352;
  float* epi = (float*)(smem + wave * WSLICE);   // aliases vh panes (WAR-safe: in-order
                                                 // per-wave DS pipe + data deps)
  float* mean_lds = (float*)(smem + MEAN_OFF);
  int b = bid >> 3;                              // 8 blocks (16 chunks) per batch

  // ---- B-fragment table build (blocks 0..255, 64 f16 each; visible after sync) ----
  if (bid < 256 && tid < 64) {
    int f = bid * 64 + tid;
    int j = f & 7;
    int ln = (f >> 3) & 63;
    int q = f >> 9;                 // 0..31 = nt*4 + ks
    int ks = q & 3, nt = q >> 2;
    int kk = ks * 32 + (ln >> 4) * 8 + j;
    int nn = nt * 16 + (ln & 15);
    Ktg[f] = (_Float16)Kmat[kk * D_CH + nn];
  }

  // ---- phase A: per chunk, mean-independent work; A-frags -> registers ----
  f16x8 a1[2][4], a2[2][4];
  f32x4 psum = {0.f, 0.f, 0.f, 0.f};
#pragma unroll
  for (int c = 0; c < 2; ++c) {
    int row0 = (2 * bid + c) * TILE;
    f32x4 yb[8], wb[8];
#pragma unroll
    for (int i = 0; i < 8; ++i) {
      size_t base = (size_t)(row0 + m0 + 2 * i + hf) * ROWLEN + c0;
      yb[i] = __builtin_nontemporal_load((const f32x4*)(x + base));
      wb[i] = __builtin_nontemporal_load((const f32x4*)(x + base + 128));
    }
#pragma unroll
    for (int i = 0; i < 8; ++i) {
      int lr = 2 * i + hf;
      int row = row0 + m0 + lr;
      psum += yb[i];
      f32x4 e;
      e[0] = __expf(wb[i][0]); e[1] = __expf(wb[i][1]);
      e[2] = __expf(wb[i][2]); e[3] = __expf(wb[i][3]);
      __builtin_nontemporal_store(e, (f32x4*)(out + (size_t)row * ROWLEN + 128 + c0));
      float s = e[0] + e[1] + e[2] + e[3];          // |w| small: no max-sub needed
      s += __shfl_xor(s, 1, 32);
      s += __shfl_xor(s, 2, 32);
      s += __shfl_xor(s, 4, 32);
      s += __shfl_xor(s, 8, 32);
      s += __shfl_xor(s, 16, 32);
      float rinv = 1.0f / s;
      f16x4 v1, v2;
      v1[0] = (_Float16)(e[0] * rinv * yb[i][0]);
      v1[1] = (_Float16)(e[1] * rinv * yb[i][1]);
      v1[2] = (_Float16)(e[2] * rinv * yb[i][2]);
      v1[3] = (_Float16)(e[3] * rinv * yb[i][3]);
      v2[0] = (_Float16)(e[0] * rinv);
      v2[1] = (_Float16)(e[1] * rinv);
      v2[2] = (_Float16)(e[2] * rinv);
      v2[3] = (_Float16)(e[3] * rinv);
      *(f16x4*)(vs1 + lr * VSTR_B + li * 8) = v1;
      *(f16x4*)(vs2 + lr * VSTR_B + li * 8) = v2;
    }
#pragma unroll
    for (int ks = 0; ks < 4; ++ks) {
      a1[c][ks] = *(const f16x8*)(vs1 + l15 * VSTR_B + ks * 64 + lg * 16);
      a2[c][ks] = *(const f16x8*)(vs2 + l15 * VSTR_B + ks * 64 + lg * 16);
    }
  }

  // ---- deterministic block partial-sum of y -> part[bid][128] ----
  __syncthreads();                                 // all waves done with their vh panes
  f32x4* scratch = (f32x4*)smem;                   // 8 groups x 32 quads = 4KB (wave0 pane)
  scratch[(wave * 2 + hf) * 32 + li] = psum;
  __syncthreads();
  if (tid < 32) {
    f32x4 t = scratch[tid];
#pragma unroll
    for (int k = 1; k < 8; ++k) t += scratch[k * 32 + tid];
    *(f32x4*)(part + (size_t)bid * D_CH + 4 * tid) = t;
  }
  __threadfence();                                 // release: drain + L2 writeback
  grid.sync();
  __threadfence();                                 // acquire: invalidate stale lines

  // ---- mean for this batch: sum 8 partials, stage in LDS ----
  if (tid < 32) {
    f32x4 t = {0.f, 0.f, 0.f, 0.f};
#pragma unroll
    for (int k = 0; k < 8; ++k)
      t += *(const f32x4*)(part + (size_t)(b * 8 + k) * D_CH + 4 * tid);
    t *= (1.0f / 1024.0f);
    *(f32x4*)(mean_lds + 4 * tid) = t;
  }
  __syncthreads();

  // ---- -mean packed to f16, aligned with B-frag k-rows (kk = ks*32 + lg*8 + j) ----
  f16x8 nm[4];
#pragma unroll
  for (int ks = 0; ks < 4; ++ks) {
    f32x4 lo = *(const f32x4*)(mean_lds + ks * 32 + lg * 8);
    f32x4 hi = *(const f32x4*)(mean_lds + ks * 32 + lg * 8 + 4);
    f16x8 m;
    m[0] = (_Float16)(-lo[0]); m[1] = (_Float16)(-lo[1]);
    m[2] = (_Float16)(-lo[2]); m[3] = (_Float16)(-lo[3]);
    m[4] = (_Float16)(-hi[0]); m[5] = (_Float16)(-hi[1]);
    m[6] = (_Float16)(-hi[2]); m[7] = (_Float16)(-hi[3]);
    nm[ks] = m;
  }

  // ---- phase B: dual MFMA into one acc; epilogue per chunk ----
#pragma unroll
  for (int c = 0; c < 2; ++c) {
    int row0 = (2 * bid + c) * TILE;
    f32x4 acc[8];
#pragma unroll
    for (int nt = 0; nt < 8; ++nt) {
      acc[nt] = (f32x4){0.f, 0.f, 0.f, 0.f};
#pragma unroll
      for (int ks = 0; ks < 4; ++ks) {
        f16x8 bf = *(const f16x8*)&Ktg[((nt * 4 + ks) * 64 + lane) * 8];
        acc[nt] = __builtin_amdgcn_mfma_f32_16x16x32_f16(a1[c][ks], bf, acc[nt], 0, 0, 0);
        f16x8 b2 = bf * nm[ks];                    // K-frag scaled by -mean[k]
        acc[nt] = __builtin_amdgcn_mfma_f32_16x16x32_f16(a2[c][ks], b2, acc[nt], 0, 0, 0);
      }
    }
#pragma unroll
    for (int nt = 0; nt < 8; ++nt)
#pragma unroll
      for (int r = 0; r < 4; ++r)
        epi[(lg * 4 + r) * EPI_W + nt * 16 + l15] = acc[nt][r];

    f32x4 yo[8];
#pragma unroll
    for (int i = 0; i < 8; ++i) {
      size_t base = (size_t)(row0 + m0 + 2 * i + hf) * ROWLEN + c0;
      yo[i] = __builtin_nontemporal_load((const f32x4*)(x + base + 256));
    }
    f32x4 mn = *(const f32x4*)(mean_lds + c0);
#pragma unroll
    for (int i = 0; i < 8; ++i) {
      int lr = 2 * i + hf;
      size_t ob = (size_t)(row0 + m0 + lr) * ROWLEN;
      f32x4 sm4 = *(const f32x4*)&epi[lr * EPI_W + c0];
      sm4 += mn;
      __builtin_nontemporal_store(sm4, (f32x4*)(out + ob + c0));           // smooth
      f32x4 yt = yo[i] - sm4;
      __builtin_nontemporal_store(yt, (f32x4*)(out + ob + 256 + c0));      // y_trans
    }
  }
}

// ============================ FALLBACK (round-2) PATH ============================
__global__ __launch_bounds__(1024) void prep_kernel(const float* __restrict__ x,
                                                    const float* __restrict__ Kmat,
                                                    float* __restrict__ meang,
                                                    _Float16* __restrict__ Ktg,
                                                    int S, int JITER) {
  int bid = blockIdx.x;
  int bh = bid / S;
  int tq = bid - bh * S;
  int b = bh >> 1, h = bh & 1;
  int tid = threadIdx.x;
  int li = tid & 15, tt = tid >> 4;
  int d4 = h * 64 + 4 * li;
  f32x4 s = {0.f, 0.f, 0.f, 0.f};
  const float* xp = x + (size_t)b * T_LEN * ROWLEN + d4;
  int t0 = tq * (T_LEN / S) + tt;
#pragma unroll 4
  for (int j = 0; j < JITER; ++j) {
    int t = t0 + 64 * j;
    f32x4 v = *(const f32x4*)(xp + (size_t)t * ROWLEN);
    s += v;
  }
  __shared__ f32x4 red[64][17];
  red[tt][li] = s;
  __syncthreads();
  for (int st = 32; st > 0; st >>= 1) {
    if (tt < st) red[tt][li] += red[tt + st][li];
    __syncthreads();
  }
  if (tt == 0) {
    f32x4 m = red[0][li] * (1.0f / 1024.0f);
    *(f32x4*)(meang + (size_t)(b * S + tq) * D_CH + d4) = m;
  }
  if (tq == 0 && tid < 64) {
    int f = bh * 64 + tid;
    int j = f & 7;
    int ln = (f >> 3) & 63;
    int q = f >> 9;
    int ks = q & 3, nt = q >> 2;
    int kk = ks * 32 + (ln >> 4) * 8 + j;
    int nn = nt * 16 + (ln & 15);
    Ktg[f] = (_Float16)Kmat[kk * D_CH + nn];
  }
}

__global__ __launch_bounds__(256, 4) void main_kernel(const float* __restrict__ x,
                                                      const float* __restrict__ meang,
                                                      const _Float16* __restrict__ Ktg,
                                                      float* __restrict__ out,
                                                      int S) {
  __shared__ alignas(16) char smem[4 * 8448];
  int tid = threadIdx.x;
  int wave = tid >> 6, lane = tid & 63;
  int hf = lane >> 5, li = lane & 31;
  int c0 = 4 * li;
  int m0 = wave * 16;
  int l15 = lane & 15, lg = lane >> 4;
  char* vslice = smem + wave * 8448;
  float* epi = (float*)(smem + wave * 8448);
  int chunk = blockIdx.x;
  int row0 = chunk * TILE;
  int bb = chunk >> 4;
  f32x4 mn = {0.f, 0.f, 0.f, 0.f};
  for (int s = 0; s < S; ++s)
    mn += *(const f32x4*)(meang + (size_t)(bb * S + s) * D_CH + c0);

  f32x4 yb[8], wb[8];
#pragma unroll
  for (int i = 0; i < 8; ++i) {
    size_t base = (size_t)(row0 + m0 + 2 * i + hf) * ROWLEN + c0;
    yb[i] = __builtin_nontemporal_load((const f32x4*)(x + base));
    wb[i] = __builtin_nontemporal_load((const f32x4*)(x + base + 128));
  }
#pragma unroll
  for (int i = 0; i < 8; ++i) {
    int lr = 2 * i + hf;
    int row = row0 + m0 + lr;
    f32x4 e;
    e[0] = __expf(wb[i][0]); e[1] = __expf(wb[i][1]);
    e[2] = __expf(wb[i][2]); e[3] = __expf(wb[i][3]);
    __builtin_nontemporal_store(e, (f32x4*)(out + (size_t)row * ROWLEN + 128 + c0));
    float s = e[0] + e[1] + e[2] + e[3];
    s += __shfl_xor(s, 1, 32);
    s += __shfl_xor(s, 2, 32);
    s += __shfl_xor(s, 4, 32);
    s += __shfl_xor(s, 8, 32);
    s += __shfl_xor(s, 16, 32);
    float rinv = 1.0f / s;
    f16x4 vh;
    vh[0] = (_Float16)(e[0] * rinv * (yb[i][0] - mn[0]));
    vh[1] = (_Float16)(e[1] * rinv * (yb[i][1] - mn[1]));
    vh[2] = (_Float16)(e[2] * rinv * (yb[i][2] - mn[2]));
    vh[3] = (_Float16)(e[3] * rinv * (yb[i][3] - mn[3]));
    *(f16x4*)(vslice + lr * VSTR_B + li * 8) = vh;
  }
  f32x4 yo[8];
#pragma unroll
  for (int i = 0; i < 8; ++i) {
    size_t base = (size_t)(row0 + m0 + 2 * i + hf) * ROWLEN + c0;
    yo[i] = __builtin_nontemporal_load((const f32x4*)(x + base + 256));
  }
  f16x8 a[4];
#pragma unroll
  for (int ks = 0; ks < 4; ++ks)
    a[ks] = *(const f16x8*)(vslice + l15 * VSTR_B + ks * 64 + lg * 16);
  f32x4 acc[8];
#pragma unroll
  for (int nt = 0; nt < 8; ++nt) {
    acc[nt] = (f32x4){0.f, 0.f, 0.f, 0.f};
#pragma unroll
    for (int ks = 0; ks < 4; ++ks) {
      f16x8 bf = *(const f16x8*)&Ktg[((nt * 4 + ks) * 64 + lane) * 8];
      acc[nt] = __builtin_amdgcn_mfma_f32_16x16x32_f16(a[ks], bf, acc[nt], 0, 0, 0);
    }
  }
#pragma unroll
  for (int nt = 0; nt < 8; ++nt)
#pragma unroll
    for (int r = 0; r < 4; ++r)
      epi[(lg * 4 + r) * EPI_W + nt * 16 + l15] = acc[nt][r];
#pragma unroll
  for (int i = 0; i < 8; ++i) {
    int lr = 2 * i + hf;
    size_t ob = (size_t)(row0 + m0 + lr) * ROWLEN;
    f32x4 sm4 = *(const f32x4*)&epi[lr * EPI_W + c0];
    sm4 += mn;
    __builtin_nontemporal_store(sm4, (f32x4*)(out + ob + c0));
    f32x4 yt = yo[i] - sm4;
    __builtin_nontemporal_store(yt, (f32x4*)(out + ob + 256 + c0));
  }
}

extern "C" void kernel_launch(void* const* d_in, const int* in_sizes, int n_in,
                              void* d_out, int out_size, void* d_ws, size_t ws_size,
                              hipStream_t stream) {
  const float* x = (const float*)d_in[0];
  const float* Kmat = (const float*)d_in[1];
  float* out = (float*)d_out;

  // Preferred: fused cooperative kernel (needs 512KB partials + 32KB Ktg workspace)
  if (ws_size >= (size_t)(512 * 1024 + 32 * 1024)) {
    float* part = (float*)d_ws;
    _Float16* Ktg = (_Float16*)((char*)d_ws + 512 * 1024);
    void* args[] = {(void*)&x, (void*)&Kmat, (void*)&part, (void*)&Ktg, (void*)&out};
    hipError_t e = hipLaunchCooperativeKernel((const void*)fused_kernel, dim3(1024),
                                              dim3(256), args, 0, stream);
    if (e == hipSuccess) return;
  }

  // Fallback: round-2 two-kernel path
  int S = (ws_size >= (size_t)(2 * 65536 + 32768)) ? 2 : 1;
  float* meang = (float*)d_ws;
  _Float16* Ktg = (_Float16*)((char*)d_ws + (size_t)S * 65536);
  prep_kernel<<<256 * S, 1024, 0, stream>>>(x, Kmat, meang, Ktg, S, 16 / S);
  main_kernel<<<NCHUNK, 256, 0, stream>>>(x, meang, Ktg, out, S);
}

// Round 4
// 360.828 us; speedup vs baseline: 1.9804x; 1.9804x over previous
//
#include <hip/hip_runtime.h>
#include <cstdint>

#define D_CH 128
#define T_LEN 1024
#define ROWLEN 384
#define NROWS (128 * 1024)
#define TILE 64
#define NCHUNK (NROWS / TILE)   // 2048
#define VSTR_B 272              // vs row stride bytes (136 f16) — conflict-free b128 reads
#define EPI_W 128               // epi rows now 128 words + XOR swizzle (was 132-pad)
#define SLICE_B 8192            // per-wave UNIFIED slice: vh pane (4352) aliases epi (8192)
                                // 4 waves * 8192 = 32768 B/block -> 5 blocks/CU (was 4)

typedef __attribute__((ext_vector_type(8))) _Float16 f16x8;
typedef __attribute__((ext_vector_type(4))) _Float16 f16x4;
typedef __attribute__((ext_vector_type(4))) float f32x4;

// Kernel A: per-(b,d) partial means over T (S-way split across blocks for 2x CU
// parallelism) + kernel matrix -> f16 in MFMA-B fragment order.
// Each partial is pre-scaled by 1/1024; main sums the S partials.
// Loads stay NORMAL (not nt) so y warms L3 for main.
__global__ __launch_bounds__(1024) void prep_kernel(const float* __restrict__ x,
                                                    const float* __restrict__ Kmat,
                                                    float* __restrict__ meang,
                                                    _Float16* __restrict__ Ktg,
                                                    int S, int JITER) {
  int bid = blockIdx.x;            // 256*S blocks: (b, half-of-D, tq)
  int bh = bid / S;
  int tq = bid - bh * S;
  int b = bh >> 1, h = bh & 1;
  int tid = threadIdx.x;
  int li = tid & 15, tt = tid >> 4;      // 16 d-groups x 64 t-slices
  int d4 = h * 64 + 4 * li;
  f32x4 s = {0.f, 0.f, 0.f, 0.f};
  const float* xp = x + (size_t)b * T_LEN * ROWLEN + d4;
  int t0 = tq * (T_LEN / S) + tt;
#pragma unroll 4
  for (int j = 0; j < JITER; ++j) {
    int t = t0 + 64 * j;
    f32x4 v = *(const f32x4*)(xp + (size_t)t * ROWLEN);
    s += v;
  }
  __shared__ f32x4 red[64][17];          // 17408 B
  red[tt][li] = s;
  __syncthreads();
  for (int st = 32; st > 0; st >>= 1) {
    if (tt < st) red[tt][li] += red[tt + st][li];
    __syncthreads();
  }
  if (tt == 0) {
    f32x4 m = red[0][li] * (1.0f / 1024.0f);
    *(f32x4*)(meang + (size_t)(b * S + tq) * D_CH + d4) = m;
  }
  // fragment-order Kt: 64 f16 per (b,h) (16384 total, bijective); tq==0 blocks only
  if (tq == 0 && tid < 64) {
    int f = bh * 64 + tid;
    int j = f & 7;
    int lane = (f >> 3) & 63;
    int q = f >> 9;                 // 0..31 = nt*4 + ks
    int ks = q & 3, nt = q >> 2;
    int kk = ks * 32 + (lane >> 4) * 8 + j;
    int nn = nt * 16 + (lane & 15);
    Ktg[f] = (_Float16)Kmat[kk * D_CH + nn];
  }
}

// Kernel B: fused softmax + MFMA matmul + vectorized epilogue. ZERO barriers.
// Round-4 changes (r3 fusion reverted — spilled frags across grid.sync):
//  - epi pane: 128-word rows + XOR bank-swizzle (col ^ (lg<<4) on write; read
//    un-swizzles with key=((lr>>2)&3)<<4). Same 2-way-max bank behavior as the
//    old 132-pad, but slice shrinks 8448->8192 B/wave: LDS 33792->32768 B/block,
//    occupancy 4 -> 5 blocks/CU (16 -> 20 waves) for this latency-bound kernel.
//  - __launch_bounds__(256,5): VGPR cap 102; peak live ~95 (yo32+a16+acc32+misc).
__global__ __launch_bounds__(256, 5) void main_kernel(const float* __restrict__ x,
                                                      const float* __restrict__ meang,
                                                      const _Float16* __restrict__ Ktg,
                                                      float* __restrict__ out,
                                                      int S) {
  __shared__ alignas(16) char smem[4 * SLICE_B];      // 32768 B -> 5 blocks/CU
  int tid = threadIdx.x;
  int wave = tid >> 6, lane = tid & 63;
  int hf = lane >> 5, li = lane & 31;
  int c0 = 4 * li;
  int m0 = wave * 16;                    // wave-private 16 rows of the 64-row tile
  int l15 = lane & 15, lg = lane >> 4;
  char* vslice = smem + wave * SLICE_B;
  float* epi = (float*)(smem + wave * SLICE_B);       // aliases vslice (WAR-safe: in-order
                                                      // per-wave DS pipe + acc data-dep)
  int chunk = blockIdx.x;                // grid == NCHUNK: one chunk per block
  int row0 = chunk * TILE;
  int bb = chunk >> 4;                   // T/TILE = 16 chunks per batch
  f32x4 mn = {0.f, 0.f, 0.f, 0.f};
  for (int s = 0; s < S; ++s)
    mn += *(const f32x4*)(meang + (size_t)(bb * S + s) * D_CH + c0);

  // ---- phase 1: load y,w; exp; store intensity; softmax; v -> LDS (f16 row-major) ----
  f32x4 yb[8], wb[8];
#pragma unroll
  for (int i = 0; i < 8; ++i) {
    size_t base = (size_t)(row0 + m0 + 2 * i + hf) * ROWLEN + c0;
    yb[i] = __builtin_nontemporal_load((const f32x4*)(x + base));
    wb[i] = __builtin_nontemporal_load((const f32x4*)(x + base + 128));
  }
#pragma unroll
  for (int i = 0; i < 8; ++i) {
    int lr = 2 * i + hf;
    int row = row0 + m0 + lr;
    f32x4 e;
    e[0] = __expf(wb[i][0]); e[1] = __expf(wb[i][1]);
    e[2] = __expf(wb[i][2]); e[3] = __expf(wb[i][3]);
    __builtin_nontemporal_store(e, (f32x4*)(out + (size_t)row * ROWLEN + 128 + c0));  // intensity
    float s = e[0] + e[1] + e[2] + e[3];                      // |w| small: no max-sub needed
    s += __shfl_xor(s, 1, 32);
    s += __shfl_xor(s, 2, 32);
    s += __shfl_xor(s, 4, 32);
    s += __shfl_xor(s, 8, 32);
    s += __shfl_xor(s, 16, 32);
    float rinv = 1.0f / s;
    f16x4 vh;
    vh[0] = (_Float16)(e[0] * rinv * (yb[i][0] - mn[0]));
    vh[1] = (_Float16)(e[1] * rinv * (yb[i][1] - mn[1]));
    vh[2] = (_Float16)(e[2] * rinv * (yb[i][2] - mn[2]));
    vh[3] = (_Float16)(e[3] * rinv * (yb[i][3] - mn[3]));
    *(f16x4*)(vslice + lr * VSTR_B + li * 8) = vh;
  }

  // ---- y_obs loads issued HERE: latency hides under LDS reads + MFMA + epi staging ----
  f32x4 yo[8];
#pragma unroll
  for (int i = 0; i < 8; ++i) {
    size_t base = (size_t)(row0 + m0 + 2 * i + hf) * ROWLEN + c0;
    yo[i] = __builtin_nontemporal_load((const f32x4*)(x + base + 256));
  }

  // ---- phase 2: A-frags from LDS, B-frags from global frag-order table (L2-hot 32KB) ----
  f16x8 a[4];
#pragma unroll
  for (int ks = 0; ks < 4; ++ks)
    a[ks] = *(const f16x8*)(vslice + l15 * VSTR_B + ks * 64 + lg * 16);
  f32x4 acc[8];
#pragma unroll
  for (int nt = 0; nt < 8; ++nt) {
    acc[nt] = (f32x4){0.f, 0.f, 0.f, 0.f};
#pragma unroll
    for (int ks = 0; ks < 4; ++ks) {
      f16x8 bf = *(const f16x8*)&Ktg[((nt * 4 + ks) * 64 + lane) * 8];
      acc[nt] = __builtin_amdgcn_mfma_f32_16x16x32_f16(a[ks], bf, acc[nt], 0, 0, 0);
    }
  }

  // ---- epilogue: C-layout -> LDS pane (XOR swizzle, 2-way max banks) ----
  // write: row = lg*4+r, col = nt*16+l15, swizzled col' = col ^ (lg<<4)
#pragma unroll
  for (int nt = 0; nt < 8; ++nt)
#pragma unroll
    for (int r = 0; r < 4; ++r)
      epi[(lg * 4 + r) * EPI_W + ((nt * 16 + l15) ^ (lg << 4))] = acc[nt][r];

#pragma unroll
  for (int i = 0; i < 8; ++i) {
    int lr = 2 * i + hf;
    int key = ((lr >> 2) & 3) << 4;      // un-swizzle: writer's lg = row>>2
    size_t ob = (size_t)(row0 + m0 + lr) * ROWLEN;
    f32x4 sm4 = *(const f32x4*)&epi[lr * EPI_W + (c0 ^ key)];
    sm4 += mn;
    __builtin_nontemporal_store(sm4, (f32x4*)(out + ob + c0));                    // smooth
    f32x4 yt = yo[i] - sm4;
    __builtin_nontemporal_store(yt, (f32x4*)(out + ob + 256 + c0));               // y_trans
  }
}

extern "C" void kernel_launch(void* const* d_in, const int* in_sizes, int n_in,
                              void* d_out, int out_size, void* d_ws, size_t ws_size,
                              hipStream_t stream) {
  const float* x = (const float*)d_in[0];
  const float* Kmat = (const float*)d_in[1];
  float* out = (float*)d_out;
  // S-way split prep needs S*64KB (partial means) + 32KB (Ktg); fall back if ws is tight
  int S = (ws_size >= (size_t)(2 * 65536 + 32768)) ? 2 : 1;
  float* meang = (float*)d_ws;                          // 128*S*128 f32
  _Float16* Ktg = (_Float16*)((char*)d_ws + (size_t)S * 65536);  // 16384 f16 (frag order)
  prep_kernel<<<256 * S, 1024, 0, stream>>>(x, Kmat, meang, Ktg, S, 16 / S);
  main_kernel<<<NCHUNK, 256, 0, stream>>>(x, meang, Ktg, out, S);
}